// Round 1
// 376.806 us; speedup vs baseline: 1.0619x; 1.0619x over previous
//
#include <hip/hip_runtime.h>

typedef unsigned short u16;
typedef __bf16 bf16x8 __attribute__((ext_vector_type(8)));
typedef float f32x4 __attribute__((ext_vector_type(4)));

#define BB 4
#define TT 4096
#define HID 1024
#define NH 16
#define HD 64
#define BT (BB*TT)          // 16384 rows
#define NCH 128             // chunks over T
#define LOG_NCH 7
#define CLEN (TT/NCH)       // 32

__device__ __forceinline__ float bf2f(u16 u) {
    return __uint_as_float(((unsigned)u) << 16);
}
__device__ __forceinline__ u16 f2bf(float f) {
    unsigned u = __float_as_uint(f);
    unsigned r = 0x7FFFu + ((u >> 16) & 1u);
    return (u16)((u + r) >> 16);
}
__device__ __forceinline__ float phi(float x) {      // elu(x)+1
    return x > 0.f ? x + 1.f : __expf(x);
}
__device__ __forceinline__ float sigmoidf(float x) {
    return 1.f / (1.f + __expf(-x));
}
__device__ __forceinline__ float4 u4_to_f4(ushort4 u) {
    return make_float4(bf2f(u.x), bf2f(u.y), bf2f(u.z), bf2f(u.w));
}

// ---------------- fused fp32 -> bf16 convert (one launch for all 4 tensors) ----------
#define CN1 (BT*HID/4)          // x      : 4194304
#define CN2 (3*HID*HID/4)       // Wqkv   :  786432
#define CN3 (HID*HID/4)         // Wgate  :  262144
#define CN4 (HID*HID/4)         // Wout   :  262144
__global__ void convert_all(const float4* __restrict__ x,    const float4* __restrict__ wqkv,
                            const float4* __restrict__ wgate, const float4* __restrict__ wout,
                            ushort4* __restrict__ xb,    ushort4* __restrict__ wqkvb,
                            ushort4* __restrict__ wgateb, ushort4* __restrict__ woutb) {
    int i = blockIdx.x * 256 + threadIdx.x;
    const float4* src; ushort4* dst; int j;
    if (i < CN1)                 { src = x;     dst = xb;     j = i; }
    else if (i < CN1+CN2)        { src = wqkv;  dst = wqkvb;  j = i - CN1; }
    else if (i < CN1+CN2+CN3)    { src = wgate; dst = wgateb; j = i - CN1 - CN2; }
    else                         { src = wout;  dst = woutb;  j = i - CN1 - CN2 - CN3; }
    float4 f = src[j];
    ushort4 u;
    u.x = f2bf(f.x); u.y = f2bf(f.y); u.z = f2bf(f.z); u.w = f2bf(f.w);
    dst[j] = u;
}

// ---------------- 256x256 MFMA GEMM, counted-vmcnt pipeline ------------------------
// C[M,N] = A[M,K] @ Bm[N,K]^T, bf16 in, 8 waves (2M x 4N), per-wave 128x64 out.
// BK=64, LDS = 2 K-tile double buffer x (A,B) x 256x64 bf16 = 128 KiB.
// Same verified XOR-chunk swizzle as before (pre-swizzled global src, linear
// global_load_lds dest, swizzled ds_read). Sync skeleton per K-tile t:
//   COMPUTE(buf[t&1])            // 24 ds_read_b128 + 64 MFMA/wave, setprio(1) wrapped
//   s_barrier                    // block-wide: reads of buf[t&1] done
//   STAGE(t+2 -> buf[t&1])       // 8 global_load_lds issued into freed buffer
//   s_waitcnt vmcnt(8)           // tile t+1 landed; the fresh 8 stay in flight
//   s_barrier                    // all waves' t+1 loads visible
// Never drains vmcnt in the main loop (T3+T4); raw s_barrier, no __syncthreads.
// EPI 0: bf16 store. EPI 1: gate epilogue. EPI 2: fp32 store.
template<int EPI>
__global__ __launch_bounds__(512, 2)
void gemm256(const u16* __restrict__ A, const u16* __restrict__ Bm,
             int M, int N, int K, void* __restrict__ Cout,
             const float* __restrict__ bg,
             const u16* __restrict__ attn,
             const u16* __restrict__ qkv)
{
    __shared__ u16 As[2][256 * 64];
    __shared__ u16 Bs[2][256 * 64];
    const int tid  = threadIdx.x;
    const int wave = tid >> 6;           // 0..7
    const int lane = tid & 63;
    const int r16  = lane & 15;
    const int m0 = blockIdx.y * 256;
    const int n0 = blockIdx.x * 256;
    const int wm = (wave & 1) * 128;     // wave row offset
    const int wn = (wave >> 1) * 64;     // wave col offset

    f32x4 acc[8][4];
    #pragma unroll
    for (int i = 0; i < 8; ++i)
        #pragma unroll
        for (int j = 0; j < 4; ++j)
            acc[i][j] = (f32x4){0.f, 0.f, 0.f, 0.f};

    // stage one K-tile (A 256x64 + B 256x64) into buffer buf: 8 loads/thread
    auto STAGE = [&](int k0, int buf) {
        #pragma unroll
        for (int j = 0; j < 4; ++j) {
            int s   = j * 8 + wave;          // segment 0..31 (8 rows each), wave-uniform
            int idx = s * 64 + lane;         // linear 16B-chunk index
            int pr  = idx >> 3;              // row 0..255
            int lc  = (idx & 7) ^ (pr & 7);  // XOR swizzle on global source
            const u16* gA = A  + (size_t)(m0 + pr) * K + k0 + lc * 8;
            const u16* gB = Bm + (size_t)(n0 + pr) * K + k0 + lc * 8;
            __builtin_amdgcn_global_load_lds(
                (const __attribute__((address_space(1))) void*)gA,
                (__attribute__((address_space(3))) void*)&As[buf][s * 512], 16, 0, 0);
            __builtin_amdgcn_global_load_lds(
                (const __attribute__((address_space(1))) void*)gB,
                (__attribute__((address_space(3))) void*)&Bs[buf][s * 512], 16, 0, 0);
        }
    };

    // one K-tile of compute from buffer buf
    auto COMPUTE = [&](int buf) {
        bf16x8 bq[4][2];
        #pragma unroll
        for (int j = 0; j < 4; ++j) {
            #pragma unroll
            for (int ks = 0; ks < 2; ++ks) {
                int lcq = ks * 4 + (lane >> 4);
                int pcq = lcq ^ (r16 & 7);
                bq[j][ks] = *(const bf16x8*)&Bs[buf][(wn + j * 16 + r16) * 64 + pcq * 8];
            }
        }
        #pragma unroll
        for (int rh = 0; rh < 2; ++rh) {
            bf16x8 af[4][2];
            #pragma unroll
            for (int i = 0; i < 4; ++i) {
                #pragma unroll
                for (int ks = 0; ks < 2; ++ks) {
                    int lcq = ks * 4 + (lane >> 4);
                    int pcq = lcq ^ (r16 & 7);
                    af[i][ks] = *(const bf16x8*)&As[buf][(wm + rh * 64 + i * 16 + r16) * 64 + pcq * 8];
                }
            }
            __builtin_amdgcn_s_setprio(1);
            #pragma unroll
            for (int i = 0; i < 4; ++i)
                #pragma unroll
                for (int j = 0; j < 4; ++j)
                    #pragma unroll
                    for (int ks = 0; ks < 2; ++ks)
                        acc[rh * 4 + i][j] = __builtin_amdgcn_mfma_f32_16x16x32_bf16(
                            af[i][ks], bq[j][ks], acc[rh * 4 + i][j], 0, 0, 0);
            __builtin_amdgcn_s_setprio(0);
        }
    };

    const int nt = K >> 6;               // K-tiles
    STAGE(0, 0);
    STAGE(64, 1);
    asm volatile("s_waitcnt vmcnt(8)" ::: "memory");   // tile 0 landed, tile 1 in flight
    __builtin_amdgcn_sched_barrier(0);
    __builtin_amdgcn_s_barrier();
    __builtin_amdgcn_sched_barrier(0);

    for (int t = 0; t < nt; ++t) {
        COMPUTE(t & 1);
        if (t + 1 < nt) {
            __builtin_amdgcn_sched_barrier(0);
            __builtin_amdgcn_s_barrier();            // reads of buf[t&1] complete
            __builtin_amdgcn_sched_barrier(0);
            if (t + 2 < nt) {
                STAGE((t + 2) << 6, t & 1);          // refill freed buffer
                asm volatile("s_waitcnt vmcnt(8)" ::: "memory");  // tile t+1 landed
            } else {
                asm volatile("s_waitcnt vmcnt(0)" ::: "memory");  // final drain
            }
            __builtin_amdgcn_sched_barrier(0);
            __builtin_amdgcn_s_barrier();            // all waves' t+1 loads visible
            __builtin_amdgcn_sched_barrier(0);
        }
    }

    // epilogue: C/D layout col=lane&15, row=(lane>>4)*4+reg
    #pragma unroll
    for (int rh = 0; rh < 2; ++rh) {
        #pragma unroll
        for (int i = 0; i < 4; ++i) {
            int rowb = m0 + wm + rh * 64 + i * 16 + (lane >> 4) * 4;
            #pragma unroll
            for (int j = 0; j < 4; ++j) {
                int col = n0 + wn + j * 16 + r16;
                #pragma unroll
                for (int r = 0; r < 4; ++r) {
                    float v = acc[rh * 4 + i][j][r];
                    size_t row = (size_t)(rowb + r);
                    if (EPI == 0) {
                        ((u16*)Cout)[row * N + col] = f2bf(v);
                    } else if (EPI == 1) {
                        float g  = sigmoidf(v + bg[col]);
                        float at = bf2f(attn[row * HID + col]);
                        float vd = bf2f(qkv[row * (3 * HID) + 2 * HID + col]);
                        ((u16*)Cout)[row * HID + col] = f2bf(g * at + (1.f - g) * vd);
                    } else {
                        ((float*)Cout)[row * N + col] = v;
                    }
                }
            }
        }
    }
}

// ---------------- scan pass A: per-chunk local finals (vectorized x4) --------------
// 16-lane group -> one (b,h,chunk); sub-lane sl handles d = sl*4..sl*4+3
__global__ void scan_finals(const u16* __restrict__ qkv, const float* __restrict__ decay_param,
                            float* __restrict__ ckv, float* __restrict__ cks) {
    int g  = blockIdx.x * 16 + (threadIdx.x >> 4);    // ((b*NH+h)*NCH + c)
    int sl = threadIdx.x & 15;
    int c = g & (NCH - 1);
    int h = (g >> LOG_NCH) & (NH - 1);
    int b = g >> (LOG_NCH + 4);
    float decay = sigmoidf(decay_param[h]);
    const u16* kp = qkv + (size_t)(b * TT + c * CLEN) * (3 * HID) + HID + h * HD + sl * 4;
    float4 skv = make_float4(0.f, 0.f, 0.f, 0.f);
    float4 sks = make_float4(0.f, 0.f, 0.f, 0.f);
    for (int t = 0; t < CLEN; ++t) {
        float4 k = u4_to_f4(*(const ushort4*)kp);
        float4 v = u4_to_f4(*(const ushort4*)(kp + HID));
        k.x = phi(k.x); k.y = phi(k.y); k.z = phi(k.z); k.w = phi(k.w);
        skv.x = decay * skv.x + k.x * v.x;  skv.y = decay * skv.y + k.y * v.y;
        skv.z = decay * skv.z + k.z * v.z;  skv.w = decay * skv.w + k.w * v.w;
        sks.x = decay * sks.x + k.x;        sks.y = decay * sks.y + k.y;
        sks.z = decay * sks.z + k.z;        sks.w = decay * sks.w + k.w;
        kp += 3 * HID;
    }
    *(float4*)(ckv + (size_t)g * 64 + sl * 4) = skv;
    *(float4*)(cks + (size_t)g * 64 + sl * 4) = sks;
}

// ---------------- scan pass B: cross-chunk exclusive prefix (in place) -------------
__global__ void scan_prefix(float* __restrict__ ckv, float* __restrict__ cks,
                            const float* __restrict__ decay_param) {
    int bh = blockIdx.x;
    int h  = bh & (NH - 1);
    int lane = threadIdx.x;
    float decay = sigmoidf(decay_param[h]);
    float dC = powf(decay, (float)CLEN);
    float* pkv = ckv + (size_t)bh * NCH * 64 + lane;
    float* pks = cks + (size_t)bh * NCH * 64 + lane;
    float fkv = 0.f, fks = 0.f;
    for (int c = 0; c < NCH; ++c) {
        float lkv = pkv[c * 64], lks = pks[c * 64];
        pkv[c * 64] = fkv; pks[c * 64] = fks;
        fkv = fkv * dC + lkv;
        fks = fks * dC + lks;
    }
}

// ---------------- scan pass C: apply with init, den-reduce, write attn (x4) --------
__global__ void scan_apply(const u16* __restrict__ qkv, const float* __restrict__ decay_param,
                           const float* __restrict__ ckv, const float* __restrict__ cks,
                           u16* __restrict__ attn) {
    int g  = blockIdx.x * 16 + (threadIdx.x >> 4);
    int sl = threadIdx.x & 15;
    int c = g & (NCH - 1);
    int h = (g >> LOG_NCH) & (NH - 1);
    int b = g >> (LOG_NCH + 4);
    float decay = sigmoidf(decay_param[h]);
    float4 skv = *(const float4*)(ckv + (size_t)g * 64 + sl * 4);
    float4 sks = *(const float4*)(cks + (size_t)g * 64 + sl * 4);
    const u16* qp = qkv + (size_t)(b * TT + c * CLEN) * (3 * HID) + h * HD + sl * 4;
    u16* op = attn + (size_t)(b * TT + c * CLEN) * HID + h * HD + sl * 4;
    for (int t = 0; t < CLEN; ++t) {
        float4 q = u4_to_f4(*(const ushort4*)qp);
        float4 k = u4_to_f4(*(const ushort4*)(qp + HID));
        float4 v = u4_to_f4(*(const ushort4*)(qp + 2 * HID));
        q.x = phi(q.x); q.y = phi(q.y); q.z = phi(q.z); q.w = phi(q.w);
        k.x = phi(k.x); k.y = phi(k.y); k.z = phi(k.z); k.w = phi(k.w);
        skv.x = decay * skv.x + k.x * v.x;  skv.y = decay * skv.y + k.y * v.y;
        skv.z = decay * skv.z + k.z * v.z;  skv.w = decay * skv.w + k.w * v.w;
        sks.x = decay * sks.x + k.x;        sks.y = decay * sks.y + k.y;
        sks.z = decay * sks.z + k.z;        sks.w = decay * sks.w + k.w;
        float s = q.x * sks.x + q.y * sks.y + q.z * sks.z + q.w * sks.w;
        s += __shfl_xor(s, 8);
        s += __shfl_xor(s, 4);
        s += __shfl_xor(s, 2);
        s += __shfl_xor(s, 1);
        float inv = 1.f / fmaxf(s, 1e-6f);
        ushort4 o;
        o.x = f2bf(q.x * skv.x * inv); o.y = f2bf(q.y * skv.y * inv);
        o.z = f2bf(q.z * skv.z * inv); o.w = f2bf(q.w * skv.w * inv);
        *(ushort4*)op = o;
        qp += 3 * HID;
        op += HID;
    }
}

extern "C" void kernel_launch(void* const* d_in, const int* in_sizes, int n_in,
                              void* d_out, int out_size, void* d_ws, size_t ws_size,
                              hipStream_t stream) {
    const float* x     = (const float*)d_in[0];   // [4,4096,1024]
    const float* Wqkv  = (const float*)d_in[1];   // [3072,1024]
    const float* Wout  = (const float*)d_in[2];   // [1024,1024]
    const float* Wgate = (const float*)d_in[3];   // [1024,1024]
    const float* bgate = (const float*)d_in[4];   // [1024]
    const float* decay = (const float*)d_in[5];   // [16]

    // workspace layout (bf16 elements)
    u16* xb     = (u16*)d_ws;                                 // 16384*1024 (aliased as attn later)
    u16* wqkvb  = xb    + (size_t)BT * HID;                   // 3072*1024
    u16* wgateb = wqkvb + (size_t)3 * HID * HID;              // 1024*1024
    u16* woutb  = wgateb + (size_t)HID * HID;                 // 1024*1024
    u16* qkvb   = woutb + (size_t)HID * HID;                  // 16384*3072
    u16* out2b  = qkvb  + (size_t)BT * 3 * HID;               // 16384*1024
    float* ckv  = (float*)(out2b + (size_t)BT * HID);         // 4*16*128*64
    float* cks  = ckv + (size_t)BB * NH * NCH * HD;
    u16* attnb  = xb;  // alias: x dead after GEMM1

    // fused converts (one launch)
    convert_all<<<(CN1 + CN2 + CN3 + CN4) / 256, 256, 0, stream>>>(
        (const float4*)x, (const float4*)Wqkv, (const float4*)Wgate, (const float4*)Wout,
        (ushort4*)xb, (ushort4*)wqkvb, (ushort4*)wgateb, (ushort4*)woutb);

    // GEMM1: qkv = x @ Wqkv^T  -> bf16 [16384,3072]  (256^2 tile, counted-vmcnt)
    gemm256<0><<<dim3(3 * HID / 256, BT / 256), 512, 0, stream>>>(
        xb, wqkvb, BT, 3 * HID, HID, qkvb, nullptr, nullptr, nullptr);

    // decay scans -> attn bf16 [16384,1024]
    scan_finals<<<BB * NH * NCH / 16, 256, 0, stream>>>(qkvb, decay, ckv, cks);
    scan_prefix<<<BB * NH, 64, 0, stream>>>(ckv, cks, decay);
    scan_apply<<<BB * NH * NCH / 16, 256, 0, stream>>>(qkvb, decay, ckv, cks, attnb);

    // GEMM2: gate + blend -> out2 bf16 [16384,1024]
    gemm256<1><<<dim3(HID / 256, BT / 256), 512, 0, stream>>>(
        attnb, wgateb, BT, HID, HID, out2b, bgate, attnb, qkvb);

    // GEMM3: final projection -> fp32 d_out
    gemm256<2><<<dim3(HID / 256, BT / 256), 512, 0, stream>>>(
        out2b, woutb, BT, HID, HID, d_out, nullptr, nullptr, nullptr);
}